// Round 10
// baseline (1157.299 us; speedup 1.0000x reference)
//
#include <hip/hip_runtime.h>
#include <hip/hip_bf16.h>
#include <math.h>

#define B_ 64
#define T_ 60
#define S_ 60
#define H_ 512
#define V_ 32000
#define L_ 2
#define BT_ (B_*T_)
#define LDSROW 40
#define LDSROW2 72   // bf16 elems per LDS row for BK=64 tiles (2-way alias only)

typedef __attribute__((ext_vector_type(8))) short short8;
typedef __attribute__((ext_vector_type(4))) float f32x4;
typedef __attribute__((ext_vector_type(4))) unsigned int u32x4;

__device__ __forceinline__ short f2bf(float x) {
  __hip_bfloat16 h = __float2bfloat16(x);
  return __builtin_bit_cast(short, h);
}
__device__ __forceinline__ float bf2f(short s) {
  unsigned int u = ((unsigned int)(unsigned short)s) << 16;
  return __builtin_bit_cast(float, u);
}
__device__ __forceinline__ float sigm(float x) { return 1.f / (1.f + __expf(-x)); }
__device__ __forceinline__ float tanh_(float x) {
  float e = __expf(-2.f * fabsf(x));
  float t = (1.f - e) / (1.f + e);
  return x >= 0.f ? t : -t;
}

// 4 x 16B loads (64B contiguous per thread). llc=true -> LLC-coherent (sc0 sc1)
__device__ __forceinline__ void ld4g(const char* p, u32x4* q, bool llc) {
  if (llc)
    asm volatile("global_load_dwordx4 %0, %4, off sc0 sc1\n\t"
                 "global_load_dwordx4 %1, %4, off offset:16 sc0 sc1\n\t"
                 "global_load_dwordx4 %2, %4, off offset:32 sc0 sc1\n\t"
                 "global_load_dwordx4 %3, %4, off offset:48 sc0 sc1"
                 : "=v"(q[0]), "=v"(q[1]), "=v"(q[2]), "=v"(q[3]) : "v"(p));
  else
    asm volatile("global_load_dwordx4 %0, %4, off sc0\n\t"
                 "global_load_dwordx4 %1, %4, off offset:16 sc0\n\t"
                 "global_load_dwordx4 %2, %4, off offset:32 sc0\n\t"
                 "global_load_dwordx4 %3, %4, off offset:48 sc0"
                 : "=v"(q[0]), "=v"(q[1]), "=v"(q[2]), "=v"(q[3]) : "v"(p));
}

#define LDSBAR() do { \
    asm volatile("s_waitcnt lgkmcnt(0)" ::: "memory"); \
    __builtin_amdgcn_s_barrier(); \
    __builtin_amdgcn_sched_barrier(0); \
  } while (0)

// ---------------- f32 -> bf16 bulk convert ----------------
__global__ __launch_bounds__(256) void convbf_k(const float* __restrict__ src,
                                                short* __restrict__ dst) {
  int g = blockIdx.x * 256 + threadIdx.x;
  const float* s = src + (size_t)g * 8;
  float4 v0 = *(const float4*)s, v1 = *(const float4*)(s + 4);
  short8 o;
  o[0]=f2bf(v0.x); o[1]=f2bf(v0.y); o[2]=f2bf(v0.z); o[3]=f2bf(v0.w);
  o[4]=f2bf(v1.x); o[5]=f2bf(v1.y); o[6]=f2bf(v1.z); o[7]=f2bf(v1.w);
  *(short8*)(dst + (size_t)g * 8) = o;
}

// ---- pack whh[2,2048,512] f32 -> block-permuted fragment-ordered bf16 ----
__global__ __launch_bounds__(256) void pack_whh_k(const float* __restrict__ whh,
                                                  short* __restrict__ pk) {
  int idx = blockIdx.x * 256 + threadIdx.x;
  int l = idx >> 17, rem = idx & 131071;
  int n = rem >> 6, k8 = rem & 63;
  int g = n >> 9, j = n & 511;
  int np = (j >> 4) * 64 + g * 16 + (j & 15);
  const float* src = whh + ((size_t)l * 2048 + n) * 512 + k8 * 8;
  float4 v0 = *(const float4*)src, v1 = *(const float4*)(src + 4);
  short8 o;
  o[0]=f2bf(v0.x); o[1]=f2bf(v0.y); o[2]=f2bf(v0.z); o[3]=f2bf(v0.w);
  o[4]=f2bf(v1.x); o[5]=f2bf(v1.y); o[6]=f2bf(v1.z); o[7]=f2bf(v1.w);
  size_t dst = (size_t)l * (2048 * 512) + ((size_t)((np >> 4) * 64 + k8)) * 128 + (np & 15) * 8;
  *(short8*)(pk + dst) = o;
}

// ---------------- embedding gather ----------------
__global__ __launch_bounds__(256) void embed_k(const int* __restrict__ idx,
                                               const float* __restrict__ emb,
                                               float* __restrict__ x) {
  int e = blockIdx.x * 256 + threadIdx.x;
  int bt = e >> 9, h = e & (H_ - 1);
  int row = idx[bt];
  x[e] = emb[(size_t)row * H_ + h];
}

// ------- C = A(f32, split hi/lo) @ Bw(f32->bf16)^T + bias1[+bias2] ----------
// XPOSE: writes xg layout [T][64 blk][8 bloc][256 nploc]
template<bool XPOSE>
__global__ __launch_bounds__(256) void gemm_a32_k(
    const float* __restrict__ A, const float* __restrict__ Bw,
    const float* __restrict__ bias1, const float* __restrict__ bias2,
    float* __restrict__ C, short* __restrict__ Cbf, int M, int N, int K) {
  __shared__ short Ahs[128 * LDSROW];
  __shared__ short Als[128 * LDSROW];
  __shared__ short Bs[128 * LDSROW];
  int tid = threadIdx.x;
  int bm = blockIdx.y * 128, bn = blockIdx.x * 128;
  int wid = tid >> 6, lane = tid & 63;
  int wr = wid >> 1, wc = wid & 1;
  int lrow = lane & 15, lk = (lane >> 4) * 8;
  f32x4 acc[4][4];
#pragma unroll
  for (int i = 0; i < 4; ++i)
#pragma unroll
    for (int j = 0; j < 4; ++j) acc[i][j] = (f32x4){0.f, 0.f, 0.f, 0.f};

  int srow = tid >> 2, scol = (tid & 3) * 8;

  for (int k0 = 0; k0 < K; k0 += 32) {
#pragma unroll
    for (int it = 0; it < 2; ++it) {
      int r = srow + it * 64;
      const float* ap = A + (size_t)(bm + r) * K + k0 + scol;
      float4 a0 = *(const float4*)ap, a1 = *(const float4*)(ap + 4);
      float av[8] = {a0.x,a0.y,a0.z,a0.w,a1.x,a1.y,a1.z,a1.w};
      short8 hv, lv;
#pragma unroll
      for (int e = 0; e < 8; ++e) {
        short h = f2bf(av[e]);
        hv[e] = h;
        lv[e] = f2bf(av[e] - bf2f(h));
      }
      *(short8*)(Ahs + r * LDSROW + scol) = hv;
      *(short8*)(Als + r * LDSROW + scol) = lv;
      const float* bp = Bw + (size_t)(bn + r) * K + k0 + scol;
      float4 b0 = *(const float4*)bp, b1 = *(const float4*)(bp + 4);
      short8 bv;
      bv[0]=f2bf(b0.x); bv[1]=f2bf(b0.y); bv[2]=f2bf(b0.z); bv[3]=f2bf(b0.w);
      bv[4]=f2bf(b1.x); bv[5]=f2bf(b1.y); bv[6]=f2bf(b1.z); bv[7]=f2bf(b1.w);
      *(short8*)(Bs + r * LDSROW + scol) = bv;
    }
    __syncthreads();
    short8 ah[4], al[4], bfr[4];
#pragma unroll
    for (int i = 0; i < 4; ++i) {
      ah[i] = *(const short8*)(Ahs + (wr * 64 + i * 16 + lrow) * LDSROW + lk);
      al[i] = *(const short8*)(Als + (wr * 64 + i * 16 + lrow) * LDSROW + lk);
    }
#pragma unroll
    for (int j = 0; j < 4; ++j)
      bfr[j] = *(const short8*)(Bs + (wc * 64 + j * 16 + lrow) * LDSROW + lk);
#pragma unroll
    for (int i = 0; i < 4; ++i)
#pragma unroll
      for (int j = 0; j < 4; ++j) {
        acc[i][j] = __builtin_amdgcn_mfma_f32_16x16x32_bf16(ah[i], bfr[j], acc[i][j], 0, 0, 0);
        acc[i][j] = __builtin_amdgcn_mfma_f32_16x16x32_bf16(al[i], bfr[j], acc[i][j], 0, 0, 0);
      }
    __syncthreads();
  }

#pragma unroll
  for (int j = 0; j < 4; ++j) {
    int col = bn + wc * 64 + j * 16 + lrow;
    float bv = bias1[col] + (bias2 ? bias2[col] : 0.f);
#pragma unroll
    for (int i = 0; i < 4; ++i) {
#pragma unroll
      for (int r = 0; r < 4; ++r) {
        int row = bm + wr * 64 + i * 16 + (lane >> 4) * 4 + r;
        float v = acc[i][j][r] + bv;
        if (XPOSE) {
          int b = row / T_, t = row - b * T_;
          int g = col >> 9, jg = col & 511;
          int c8 = b >> 3, bloc = b & 7, q = jg >> 6;
          int nploc = ((jg >> 4) & 3) * 64 + g * 16 + (jg & 15);
          C[(((size_t)t * 64 + q * 8 + c8) * 8 + bloc) * 256 + nploc] = v;
        } else {
          C[(size_t)row * N + col] = v;
          if (Cbf) Cbf[(size_t)row * N + col] = f2bf(v);
        }
      }
    }
  }
}

// --------- final: C = A(bf16) @ Bbf(bf16)^T + bias, BK=64, nt C-stores ------
__global__ __launch_bounds__(256) void gemm_bb_k(
    const short* __restrict__ A, const short* __restrict__ Bbf,
    const float* __restrict__ bias, float* __restrict__ C) {
  const int N = V_, K = H_;
  int n = blockIdx.x;
  int xcd = n & 7, pos = n >> 3;
  int base = (xcd < 4) ? xcd * 938 : 4 * 938 + (xcd - 4) * 937;
  int wg = base + pos;
  int bm = (wg % 30) * 128;
  int bn = (wg / 30) * 128;

  __shared__ short As[128 * LDSROW2];
  __shared__ short Bs[128 * LDSROW2];
  int tid = threadIdx.x;
  int wid = tid >> 6, lane = tid & 63;
  int wr = wid >> 1, wc = wid & 1;
  int lrow = lane & 15;
  f32x4 acc[4][4];
#pragma unroll
  for (int i = 0; i < 4; ++i)
#pragma unroll
    for (int j = 0; j < 4; ++j) acc[i][j] = (f32x4){0.f, 0.f, 0.f, 0.f};

  int srow = tid >> 2, scol = (tid & 3) * 16;

  for (int k0 = 0; k0 < K; k0 += 64) {
#pragma unroll
    for (int it = 0; it < 2; ++it) {
      int r = srow + it * 64;
      const short* ap = A + (size_t)(bm + r) * K + k0 + scol;
      short8 a0 = *(const short8*)ap, a1 = *(const short8*)(ap + 8);
      *(short8*)(As + r * LDSROW2 + scol) = a0;
      *(short8*)(As + r * LDSROW2 + scol + 8) = a1;
      const short* bp = Bbf + (size_t)(bn + r) * K + k0 + scol;
      short8 b0 = *(const short8*)bp, b1 = *(const short8*)(bp + 8);
      *(short8*)(Bs + r * LDSROW2 + scol) = b0;
      *(short8*)(Bs + r * LDSROW2 + scol + 8) = b1;
    }
    __syncthreads();
#pragma unroll
    for (int kk = 0; kk < 2; ++kk) {
      int lk = kk * 32 + (lane >> 4) * 8;
      short8 af[4], bfr[4];
#pragma unroll
      for (int i = 0; i < 4; ++i)
        af[i] = *(const short8*)(As + (wr * 64 + i * 16 + lrow) * LDSROW2 + lk);
#pragma unroll
      for (int j = 0; j < 4; ++j)
        bfr[j] = *(const short8*)(Bs + (wc * 64 + j * 16 + lrow) * LDSROW2 + lk);
#pragma unroll
      for (int i = 0; i < 4; ++i)
#pragma unroll
        for (int j = 0; j < 4; ++j)
          acc[i][j] = __builtin_amdgcn_mfma_f32_16x16x32_bf16(af[i], bfr[j], acc[i][j], 0, 0, 0);
    }
    __syncthreads();
  }

#pragma unroll
  for (int j = 0; j < 4; ++j) {
    int col = bn + wc * 64 + j * 16 + lrow;
    float bv = bias[col];
#pragma unroll
    for (int i = 0; i < 4; ++i)
#pragma unroll
      for (int r = 0; r < 4; ++r) {
        int row = bm + wr * 64 + i * 16 + (lane >> 4) * 4 + r;
        float v = acc[i][j][r] + bv;
        float* cp = C + (size_t)row * N + col;
        asm volatile("global_store_dword %0, %1, off nt" :: "v"(cp), "v"(v) : "memory");
      }
  }
}

// ---- persistent LSTM: 8 intra-XCD groups x 8 j-blocks, tagged granules ----
// Role split: waves 0-3 load/poll h + MFMA + epilogue (NO sc1 stores);
// waves 4-7 MFMA + publish staged h via sc0+sc1 stores and NEVER wait vmcnt,
// so LLC store acks pipeline in the background (the r9 critical-path fix).
__global__ __launch_bounds__(512, 2) void lstm_seq_k(
    const float* __restrict__ xg,      // [T][64 blk][8 bloc][256 nploc]
    const short* __restrict__ whh_pk,  // packed bf16
    char* __restrict__ hx,             // 8 groups x 2 x 32KB, zeroed per layer
    float* __restrict__ dec) {         // [B,T,H]
  __shared__ short hhi[16][520];
  __shared__ short hlo[16][520];
  __shared__ float gates[256][20];
  __shared__ unsigned hstg[2][256];    // staged {hi,lo} words, slot=epilogue tid
  const int tid = threadIdx.x;
  const int bid = blockIdx.x;
  const int c = bid & 7, q = bid >> 3;
  const int w = tid >> 6, lane = tid & 63;
  const int lr = lane & 15, lkg = lane >> 4;

  for (int i = tid; i < 16 * 520; i += 512) {
    ((short*)hhi)[i] = 0;
    ((short*)hlo)[i] = 0;
  }

  // weights: wave w owns row-tiles q*16 + {w*2, w*2+1}, full K
  short8 wreg[2][16];
#pragma unroll
  for (int nt = 0; nt < 2; ++nt)
#pragma unroll
    for (int kt = 0; kt < 16; ++kt)
      wreg[nt][kt] = *(const short8*)(whh_pk +
          ((size_t)((q * 16 + w * 2 + nt) * 64 + kt * 4 + lkg)) * 128 + lr * 8);

  const bool ldw = (tid < 256);
  // epilogue ids (tid<256)
  const int bloc_e = tid & 7;
  const int p_e = (tid >> 3) & 31;
  const int j0 = p_e * 2;
  // loader ids (tid<256): 8 granules (128B) each
  const int lbloc = tid >> 5;
  const int lj16 = (tid & 31) * 16;
  // storer ids (tid>=256)
  const int s = tid - 256;
  const int sbloc = s & 7, sp = (s >> 3) & 31;
  char* grp = hx + (size_t)c * 65536;
  char* sgran = grp + ((size_t)(sbloc * 256 + q * 32 + sp)) * 16;

  float cc0 = 0.f, cc1 = 0.f;
  __syncthreads();

  for (int t = 0; t < T_; ++t) {
    const unsigned tgt = (unsigned)t;
    float2 xgv[4];
    if (ldw) {
      // xg(t) loads first (plain; latency hides under tag-wait + MFMA)
      const float* xb = xg + ((size_t)t * 64 + bid) * 2048 + bloc_e * 256;
      int rw0 = (j0 >> 4) * 64 + (j0 & 15);
#pragma unroll
      for (int g = 0; g < 4; ++g) xgv[g] = *(const float2*)(xb + rw0 + g * 16);
      asm volatile("" ::: "memory");   // keep xg issue ahead of h loads

      // ---- poll/load h(t): 8 granules = 128B/thread ----
      const char* pth = grp + (size_t)(t & 1) * 32768 + (size_t)tid * 128;
      u32x4 qg[8];
      ld4g(pth, qg, false);
      ld4g(pth + 64, qg + 4, false);
      for (unsigned a = 0;; ++a) {
        asm volatile("s_waitcnt vmcnt(0)" ::: "memory");
        __builtin_amdgcn_sched_barrier(0);
        unsigned bad = 0;
#pragma unroll
        for (int i = 0; i < 8; ++i) bad |= (qg[i][2] ^ tgt);
        if (!bad) break;
        __builtin_amdgcn_s_sleep(1);
        bool llc = (a & 1) != 0;
        ld4g(pth, qg, llc);
        ld4g(pth + 64, qg + 4, llc);
      }
      u32x4 hi0 = {qg[0][0], qg[1][0], qg[2][0], qg[3][0]};
      u32x4 hi1 = {qg[4][0], qg[5][0], qg[6][0], qg[7][0]};
      u32x4 lo0 = {qg[0][1], qg[1][1], qg[2][1], qg[3][1]};
      u32x4 lo1 = {qg[4][1], qg[5][1], qg[6][1], qg[7][1]};
      *(u32x4*)(&hhi[lbloc][lj16])     = hi0;
      *(u32x4*)(&hhi[lbloc][lj16 + 8]) = hi1;
      *(u32x4*)(&hlo[lbloc][lj16])     = lo0;
      *(u32x4*)(&hlo[lbloc][lj16 + 8]) = lo1;
    } else if (t > 0) {
      // ---- publish h(t) staged last step; never wait on these acks ----
      u32x4 hv;
      hv[0] = hstg[0][s];
      hv[1] = hstg[1][s];
      hv[2] = tgt;
      hv[3] = tgt;
      char* pb = sgran + (size_t)(t & 1) * 32768;
      asm volatile("global_store_dwordx4 %0, %1, off sc0" :: "v"(pb), "v"(hv) : "memory");
      asm volatile("global_store_dwordx4 %0, %1, off sc0 sc1" :: "v"(pb), "v"(hv) : "memory");
    }
    LDSBAR();   // h(t) in LDS for all waves

    // ---- MFMA: gates_partial = h @ whh_slice (all 8 waves) ----
    f32x4 acc[2];
    acc[0] = (f32x4){0.f, 0.f, 0.f, 0.f};
    acc[1] = (f32x4){0.f, 0.f, 0.f, 0.f};
#pragma unroll
    for (int kt = 0; kt < 16; ++kt) {
      short8 ah = *(const short8*)(&hhi[lr][kt * 32 + lkg * 8]);
      short8 al = *(const short8*)(&hlo[lr][kt * 32 + lkg * 8]);
#pragma unroll
      for (int nt = 0; nt < 2; ++nt) {
        acc[nt] = __builtin_amdgcn_mfma_f32_16x16x32_bf16(ah, wreg[nt][kt], acc[nt], 0, 0, 0);
        acc[nt] = __builtin_amdgcn_mfma_f32_16x16x32_bf16(al, wreg[nt][kt], acc[nt], 0, 0, 0);
      }
    }
#pragma unroll
    for (int nt = 0; nt < 2; ++nt)
      *(f32x4*)(&gates[(w * 2 + nt) * 16 + lr][lkg * 4]) = acc[nt];
    LDSBAR();

    // ---- epilogue: waves 0-3 only ----
    if (ldw) {
      float gv0[4], gv1[4];
      int rw0 = (j0 >> 4) * 64 + (j0 & 15);
#pragma unroll
      for (int g = 0; g < 4; ++g) {
        int rw = rw0 + g * 16;
        gv0[g] = gates[rw][bloc_e] + xgv[g].x;
        gv1[g] = gates[rw + 1][bloc_e] + xgv[g].y;
      }
      float cn0 = sigm(gv0[1]) * cc0 + sigm(gv0[0]) * tanh_(gv0[2]);
      float hn0 = sigm(gv0[3]) * tanh_(cn0);
      cc0 = cn0;
      float cn1 = sigm(gv1[1]) * cc1 + sigm(gv1[0]) * tanh_(gv1[2]);
      float hn1 = sigm(gv1[3]) * tanh_(cn1);
      cc1 = cn1;
      short hi0 = f2bf(hn0), hi1 = f2bf(hn1);
      short lo0 = f2bf(hn0 - bf2f(hi0)), lo1 = f2bf(hn1 - bf2f(hi1));
      hstg[0][tid] = (unsigned)(unsigned short)hi0 |
                     ((unsigned)(unsigned short)hi1 << 16);
      hstg[1][tid] = (unsigned)(unsigned short)lo0 |
                     ((unsigned)(unsigned short)lo1 << 16);
      float2 dv; dv.x = hn0; dv.y = hn1;
      *(float2*)(dec + ((size_t)(c * 8 + bloc_e) * T_ + t) * H_ + q * 64 + j0) = dv;
    }
    LDSBAR();   // staging visible to storer waves at top of t+1
  }
}

// ---------------- attention + softmax + concat (f32) ----------------
__global__ __launch_bounds__(256) void attn_k(const float* __restrict__ dec,
                                              const float* __restrict__ enc,
                                              const int* __restrict__ lens,
                                              float* __restrict__ cat) {
  int bt = blockIdx.x;
  int b = bt / T_;
  __shared__ float dsh[H_];
  __shared__ float p[64];
  int tid = threadIdx.x;
  dsh[tid] = dec[(size_t)bt * H_ + tid];
  dsh[tid + 256] = dec[(size_t)bt * H_ + tid + 256];
  __syncthreads();
  int wid = tid >> 6, lane = tid & 63;
  int len = lens[b];
  for (int s = wid; s < S_; s += 4) {
    const float* er = enc + ((size_t)(b * S_ + s)) * H_ + lane * 8;
    float4 e0 = *(const float4*)er, e1 = *(const float4*)(er + 4);
    const float* dr = dsh + lane * 8;
    float sum = e0.x*dr[0] + e0.y*dr[1] + e0.z*dr[2] + e0.w*dr[3]
              + e1.x*dr[4] + e1.y*dr[5] + e1.z*dr[6] + e1.w*dr[7];
#pragma unroll
    for (int off = 32; off > 0; off >>= 1) sum += __shfl_down(sum, off);
    if (lane == 0) p[s] = sum + (s < len ? 0.f : -1.0e9f);
  }
  __syncthreads();
  if (wid == 0) {
    float v = (lane < S_) ? p[lane] : -INFINITY;
    float m = v;
#pragma unroll
    for (int off = 32; off > 0; off >>= 1) m = fmaxf(m, __shfl_down(m, off));
    m = __shfl(m, 0);
    float e = (lane < S_) ? expf(v - m) : 0.f;
    float ssum = e;
#pragma unroll
    for (int off = 32; off > 0; off >>= 1) ssum += __shfl_down(ssum, off);
    ssum = __shfl(ssum, 0);
    if (lane < S_) p[lane] = e / ssum;
  }
  __syncthreads();
  int h = tid * 2;
  float a0 = 0.f, a1 = 0.f;
  for (int s = 0; s < S_; ++s) {
    float ps = p[s];
    const float* er = enc + ((size_t)(b * S_ + s)) * H_ + h;
    a0 += ps * er[0];
    a1 += ps * er[1];
  }
  size_t base = (size_t)bt * (2 * H_);
  cat[base + h]          = dsh[h];
  cat[base + h + 1]      = dsh[h + 1];
  cat[base + H_ + h]     = a0;
  cat[base + H_ + h + 1] = a1;
}

extern "C" void kernel_launch(void* const* d_in, const int* in_sizes, int n_in,
                              void* d_out, int out_size, void* d_ws, size_t ws_size,
                              hipStream_t stream) {
  (void)in_sizes; (void)n_in; (void)out_size; (void)ws_size;
  const int*   indices = (const int*)d_in[0];
  const float* enc     = (const float*)d_in[1];
  const int*   de_lens = (const int*)d_in[2];
  const float* emb     = (const float*)d_in[3];
  const float* w_ih    = (const float*)d_in[4];
  const float* w_hh    = (const float*)d_in[5];
  const float* b_ih    = (const float*)d_in[6];
  const float* b_hh    = (const float*)d_in[7];
  const float* lin_w   = (const float*)d_in[8];
  const float* lin_b   = (const float*)d_in[9];
  const float* out_w   = (const float*)d_in[10];
  const float* out_b   = (const float*)d_in[11];
  float* outp = (float*)d_out;

  char* ws = (char*)d_ws;
  size_t off = 0;
  auto alloc = [&](size_t bytes) -> void* {
    void* p = ws + off; off += (bytes + 255) & ~(size_t)255; return p;
  };
  float* x      = (float*)alloc((size_t)BT_ * H_ * 4);
  float* xg     = (float*)alloc((size_t)BT_ * 4 * H_ * 4);      // [T,64,8,256]
  float* dec    = (float*)alloc((size_t)BT_ * H_ * 4);          // [B,T,H]
  float* cat    = (float*)alloc((size_t)BT_ * 2 * H_ * 4);
  short* ow_bf  = (short*)alloc((size_t)V_ * H_ * 2);
  short* whh_pk = (short*)alloc((size_t)L_ * 4 * H_ * H_ * 2);
  short* x_bf   = (short*)alloc((size_t)BT_ * H_ * 2);
  char*  hx     = (char*)alloc((size_t)8 * 2 * 32768);          // 512KB granules

  convbf_k<<<V_ * H_ / 8 / 256, 256, 0, stream>>>(out_w, ow_bf);
  pack_whh_k<<<L_ * 2048 * 64 / 256, 256, 0, stream>>>(w_hh, whh_pk);
  embed_k<<<BT_ * H_ / 256, 256, 0, stream>>>(indices, emb, x);

  for (int l = 0; l < L_; ++l) {
    gemm_a32_k<true><<<dim3(4 * H_ / 128, BT_ / 128), 256, 0, stream>>>(
        x, w_ih + (size_t)l * 4 * H_ * H_, b_ih + l * 4 * H_, b_hh + l * 4 * H_,
        xg, nullptr, BT_, 4 * H_, H_);
    hipMemsetAsync(hx, 0, (size_t)8 * 2 * 32768, stream);   // zero both parities
    lstm_seq_k<<<64, 512, 0, stream>>>(
        xg, whh_pk + (size_t)l * 4 * H_ * H_, hx, dec);
    attn_k<<<BT_, 256, 0, stream>>>(dec, enc, de_lens, cat);
    gemm_a32_k<false><<<dim3(H_ / 128, BT_ / 128), 256, 0, stream>>>(
        cat, lin_w + (size_t)l * H_ * 2 * H_, lin_b + l * H_, nullptr,
        x, (l == L_ - 1) ? x_bf : nullptr, BT_, H_, 2 * H_);
  }

  gemm_bb_k<<<30 * (V_ / 128), 256, 0, stream>>>(x_bf, ow_bf, out_b, outp);
}

// Round 11
// 979.954 us; speedup vs baseline: 1.1810x; 1.1810x over previous
//
#include <hip/hip_runtime.h>
#include <hip/hip_bf16.h>
#include <math.h>

#define B_ 64
#define T_ 60
#define S_ 60
#define H_ 512
#define V_ 32000
#define L_ 2
#define BT_ (B_*T_)
#define LDSROW 40
#define LDSROW2 72   // bf16 elems per LDS row for BK=64 tiles (2-way alias only)

typedef __attribute__((ext_vector_type(8))) short short8;
typedef __attribute__((ext_vector_type(4))) float f32x4;
typedef __attribute__((ext_vector_type(4))) unsigned int u32x4;

__device__ __forceinline__ short f2bf(float x) {
  __hip_bfloat16 h = __float2bfloat16(x);
  return __builtin_bit_cast(short, h);
}
__device__ __forceinline__ float bf2f(short s) {
  unsigned int u = ((unsigned int)(unsigned short)s) << 16;
  return __builtin_bit_cast(float, u);
}
__device__ __forceinline__ float sigm(float x) { return 1.f / (1.f + __expf(-x)); }
__device__ __forceinline__ float tanh_(float x) {
  float e = __expf(-2.f * fabsf(x));
  float t = (1.f - e) / (1.f + e);
  return x >= 0.f ? t : -t;
}

// 4 x 16B loads (64B contiguous per thread). llc=true -> LLC-coherent (sc0 sc1)
__device__ __forceinline__ void ld4g(const char* p, u32x4* q, bool llc) {
  if (llc)
    asm volatile("global_load_dwordx4 %0, %4, off sc0 sc1\n\t"
                 "global_load_dwordx4 %1, %4, off offset:16 sc0 sc1\n\t"
                 "global_load_dwordx4 %2, %4, off offset:32 sc0 sc1\n\t"
                 "global_load_dwordx4 %3, %4, off offset:48 sc0 sc1"
                 : "=v"(q[0]), "=v"(q[1]), "=v"(q[2]), "=v"(q[3]) : "v"(p));
  else
    asm volatile("global_load_dwordx4 %0, %4, off sc0\n\t"
                 "global_load_dwordx4 %1, %4, off offset:16 sc0\n\t"
                 "global_load_dwordx4 %2, %4, off offset:32 sc0\n\t"
                 "global_load_dwordx4 %3, %4, off offset:48 sc0"
                 : "=v"(q[0]), "=v"(q[1]), "=v"(q[2]), "=v"(q[3]) : "v"(p));
}

#define LDSBAR() do { \
    asm volatile("s_waitcnt lgkmcnt(0)" ::: "memory"); \
    __builtin_amdgcn_s_barrier(); \
    __builtin_amdgcn_sched_barrier(0); \
  } while (0)

// ---------------- f32 -> bf16 bulk convert ----------------
__global__ __launch_bounds__(256) void convbf_k(const float* __restrict__ src,
                                                short* __restrict__ dst) {
  int g = blockIdx.x * 256 + threadIdx.x;
  const float* s = src + (size_t)g * 8;
  float4 v0 = *(const float4*)s, v1 = *(const float4*)(s + 4);
  short8 o;
  o[0]=f2bf(v0.x); o[1]=f2bf(v0.y); o[2]=f2bf(v0.z); o[3]=f2bf(v0.w);
  o[4]=f2bf(v1.x); o[5]=f2bf(v1.y); o[6]=f2bf(v1.z); o[7]=f2bf(v1.w);
  *(short8*)(dst + (size_t)g * 8) = o;
}

// ---- pack whh[2,2048,512] f32 -> block-permuted fragment-ordered bf16 ----
__global__ __launch_bounds__(256) void pack_whh_k(const float* __restrict__ whh,
                                                  short* __restrict__ pk) {
  int idx = blockIdx.x * 256 + threadIdx.x;
  int l = idx >> 17, rem = idx & 131071;
  int n = rem >> 6, k8 = rem & 63;
  int g = n >> 9, j = n & 511;
  int np = (j >> 4) * 64 + g * 16 + (j & 15);
  const float* src = whh + ((size_t)l * 2048 + n) * 512 + k8 * 8;
  float4 v0 = *(const float4*)src, v1 = *(const float4*)(src + 4);
  short8 o;
  o[0]=f2bf(v0.x); o[1]=f2bf(v0.y); o[2]=f2bf(v0.z); o[3]=f2bf(v0.w);
  o[4]=f2bf(v1.x); o[5]=f2bf(v1.y); o[6]=f2bf(v1.z); o[7]=f2bf(v1.w);
  size_t dst = (size_t)l * (2048 * 512) + ((size_t)((np >> 4) * 64 + k8)) * 128 + (np & 15) * 8;
  *(short8*)(pk + dst) = o;
}

// ---------------- embedding gather ----------------
__global__ __launch_bounds__(256) void embed_k(const int* __restrict__ idx,
                                               const float* __restrict__ emb,
                                               float* __restrict__ x) {
  int e = blockIdx.x * 256 + threadIdx.x;
  int bt = e >> 9, h = e & (H_ - 1);
  int row = idx[bt];
  x[e] = emb[(size_t)row * H_ + h];
}

// ------- C = A(f32, split hi/lo) @ Bw(f32->bf16)^T + bias1[+bias2] ----------
// XPOSE: writes xg layout [T][64 blk][8 bloc][256 nploc]
template<bool XPOSE>
__global__ __launch_bounds__(256) void gemm_a32_k(
    const float* __restrict__ A, const float* __restrict__ Bw,
    const float* __restrict__ bias1, const float* __restrict__ bias2,
    float* __restrict__ C, short* __restrict__ Cbf, int M, int N, int K) {
  __shared__ short Ahs[128 * LDSROW];
  __shared__ short Als[128 * LDSROW];
  __shared__ short Bs[128 * LDSROW];
  int tid = threadIdx.x;
  int bm = blockIdx.y * 128, bn = blockIdx.x * 128;
  int wid = tid >> 6, lane = tid & 63;
  int wr = wid >> 1, wc = wid & 1;
  int lrow = lane & 15, lk = (lane >> 4) * 8;
  f32x4 acc[4][4];
#pragma unroll
  for (int i = 0; i < 4; ++i)
#pragma unroll
    for (int j = 0; j < 4; ++j) acc[i][j] = (f32x4){0.f, 0.f, 0.f, 0.f};

  int srow = tid >> 2, scol = (tid & 3) * 8;

  for (int k0 = 0; k0 < K; k0 += 32) {
#pragma unroll
    for (int it = 0; it < 2; ++it) {
      int r = srow + it * 64;
      const float* ap = A + (size_t)(bm + r) * K + k0 + scol;
      float4 a0 = *(const float4*)ap, a1 = *(const float4*)(ap + 4);
      float av[8] = {a0.x,a0.y,a0.z,a0.w,a1.x,a1.y,a1.z,a1.w};
      short8 hv, lv;
#pragma unroll
      for (int e = 0; e < 8; ++e) {
        short h = f2bf(av[e]);
        hv[e] = h;
        lv[e] = f2bf(av[e] - bf2f(h));
      }
      *(short8*)(Ahs + r * LDSROW + scol) = hv;
      *(short8*)(Als + r * LDSROW + scol) = lv;
      const float* bp = Bw + (size_t)(bn + r) * K + k0 + scol;
      float4 b0 = *(const float4*)bp, b1 = *(const float4*)(bp + 4);
      short8 bv;
      bv[0]=f2bf(b0.x); bv[1]=f2bf(b0.y); bv[2]=f2bf(b0.z); bv[3]=f2bf(b0.w);
      bv[4]=f2bf(b1.x); bv[5]=f2bf(b1.y); bv[6]=f2bf(b1.z); bv[7]=f2bf(b1.w);
      *(short8*)(Bs + r * LDSROW + scol) = bv;
    }
    __syncthreads();
    short8 ah[4], al[4], bfr[4];
#pragma unroll
    for (int i = 0; i < 4; ++i) {
      ah[i] = *(const short8*)(Ahs + (wr * 64 + i * 16 + lrow) * LDSROW + lk);
      al[i] = *(const short8*)(Als + (wr * 64 + i * 16 + lrow) * LDSROW + lk);
    }
#pragma unroll
    for (int j = 0; j < 4; ++j)
      bfr[j] = *(const short8*)(Bs + (wc * 64 + j * 16 + lrow) * LDSROW + lk);
#pragma unroll
    for (int i = 0; i < 4; ++i)
#pragma unroll
      for (int j = 0; j < 4; ++j) {
        acc[i][j] = __builtin_amdgcn_mfma_f32_16x16x32_bf16(ah[i], bfr[j], acc[i][j], 0, 0, 0);
        acc[i][j] = __builtin_amdgcn_mfma_f32_16x16x32_bf16(al[i], bfr[j], acc[i][j], 0, 0, 0);
      }
    __syncthreads();
  }

#pragma unroll
  for (int j = 0; j < 4; ++j) {
    int col = bn + wc * 64 + j * 16 + lrow;
    float bv = bias1[col] + (bias2 ? bias2[col] : 0.f);
#pragma unroll
    for (int i = 0; i < 4; ++i) {
#pragma unroll
      for (int r = 0; r < 4; ++r) {
        int row = bm + wr * 64 + i * 16 + (lane >> 4) * 4 + r;
        float v = acc[i][j][r] + bv;
        if (XPOSE) {
          int b = row / T_, t = row - b * T_;
          int g = col >> 9, jg = col & 511;
          int c8 = b >> 3, bloc = b & 7, q = jg >> 6;
          int nploc = ((jg >> 4) & 3) * 64 + g * 16 + (jg & 15);
          C[(((size_t)t * 64 + q * 8 + c8) * 8 + bloc) * 256 + nploc] = v;
        } else {
          C[(size_t)row * N + col] = v;
          if (Cbf) Cbf[(size_t)row * N + col] = f2bf(v);
        }
      }
    }
  }
}

// --------- final: C = A(bf16) @ Bbf(bf16)^T + bias, BK=64, nt C-stores ------
__global__ __launch_bounds__(256) void gemm_bb_k(
    const short* __restrict__ A, const short* __restrict__ Bbf,
    const float* __restrict__ bias, float* __restrict__ C) {
  const int N = V_, K = H_;
  int n = blockIdx.x;
  int xcd = n & 7, pos = n >> 3;
  int base = (xcd < 4) ? xcd * 938 : 4 * 938 + (xcd - 4) * 937;
  int wg = base + pos;
  int bm = (wg % 30) * 128;
  int bn = (wg / 30) * 128;

  __shared__ short As[128 * LDSROW2];
  __shared__ short Bs[128 * LDSROW2];
  int tid = threadIdx.x;
  int wid = tid >> 6, lane = tid & 63;
  int wr = wid >> 1, wc = wid & 1;
  int lrow = lane & 15;
  f32x4 acc[4][4];
#pragma unroll
  for (int i = 0; i < 4; ++i)
#pragma unroll
    for (int j = 0; j < 4; ++j) acc[i][j] = (f32x4){0.f, 0.f, 0.f, 0.f};

  int srow = tid >> 2, scol = (tid & 3) * 16;

  for (int k0 = 0; k0 < K; k0 += 64) {
#pragma unroll
    for (int it = 0; it < 2; ++it) {
      int r = srow + it * 64;
      const short* ap = A + (size_t)(bm + r) * K + k0 + scol;
      short8 a0 = *(const short8*)ap, a1 = *(const short8*)(ap + 8);
      *(short8*)(As + r * LDSROW2 + scol) = a0;
      *(short8*)(As + r * LDSROW2 + scol + 8) = a1;
      const short* bp = Bbf + (size_t)(bn + r) * K + k0 + scol;
      short8 b0 = *(const short8*)bp, b1 = *(const short8*)(bp + 8);
      *(short8*)(Bs + r * LDSROW2 + scol) = b0;
      *(short8*)(Bs + r * LDSROW2 + scol + 8) = b1;
    }
    __syncthreads();
#pragma unroll
    for (int kk = 0; kk < 2; ++kk) {
      int lk = kk * 32 + (lane >> 4) * 8;
      short8 af[4], bfr[4];
#pragma unroll
      for (int i = 0; i < 4; ++i)
        af[i] = *(const short8*)(As + (wr * 64 + i * 16 + lrow) * LDSROW2 + lk);
#pragma unroll
      for (int j = 0; j < 4; ++j)
        bfr[j] = *(const short8*)(Bs + (wc * 64 + j * 16 + lrow) * LDSROW2 + lk);
#pragma unroll
      for (int i = 0; i < 4; ++i)
#pragma unroll
        for (int j = 0; j < 4; ++j)
          acc[i][j] = __builtin_amdgcn_mfma_f32_16x16x32_bf16(af[i], bfr[j], acc[i][j], 0, 0, 0);
    }
    __syncthreads();
  }

#pragma unroll
  for (int j = 0; j < 4; ++j) {
    int col = bn + wc * 64 + j * 16 + lrow;
    float bv = bias[col];
#pragma unroll
    for (int i = 0; i < 4; ++i)
#pragma unroll
      for (int r = 0; r < 4; ++r) {
        int row = bm + wr * 64 + i * 16 + (lane >> 4) * 4 + r;
        float v = acc[i][j][r] + bv;
        float* cp = C + (size_t)row * N + col;
        asm volatile("global_store_dword %0, %1, off nt" :: "v"(cp), "v"(v) : "memory");
      }
  }
}

// ---- persistent LSTM: 8 intra-XCD groups x 8 j-blocks, tagged granules ----
// r11 role split: waves 4-7 (store-free) do the tag-poll + h load of the FULL
// group buffer (two r8-mapped 64B chunks each) so their vmcnt(0) never waits
// on store acks; waves 0-3 issue xg loads early (no wait), run the epilogue
// and publish h IMMEDIATELY (r8 timing) via sc0 + sc0sc1 stores; their store
// acks drain in background, first waited one full phase later (xg use).
__global__ __launch_bounds__(512, 2) void lstm_seq_k(
    const float* __restrict__ xg,      // [T][64 blk][8 bloc][256 nploc]
    const short* __restrict__ whh_pk,  // packed bf16
    char* __restrict__ hx,             // 8 groups x 2 x 32KB, zeroed per layer
    float* __restrict__ dec) {         // [B,T,H]
  __shared__ short hhi[16][520];
  __shared__ short hlo[16][520];
  __shared__ float gates[256][20];
  const int tid = threadIdx.x;
  const int bid = blockIdx.x;
  const int c = bid & 7, q = bid >> 3;
  const int w = tid >> 6, lane = tid & 63;
  const int lr = lane & 15, lkg = lane >> 4;

  for (int i = tid; i < 16 * 520; i += 512) {
    ((short*)hhi)[i] = 0;
    ((short*)hlo)[i] = 0;
  }

  // weights: wave w owns row-tiles q*16 + {w*2, w*2+1}, full K
  short8 wreg[2][16];
#pragma unroll
  for (int nt = 0; nt < 2; ++nt)
#pragma unroll
    for (int kt = 0; kt < 16; ++kt)
      wreg[nt][kt] = *(const short8*)(whh_pk +
          ((size_t)((q * 16 + w * 2 + nt) * 64 + kt * 4 + lkg)) * 128 + lr * 8);

  const bool epi = (tid < 256);
  // epilogue ids (tid<256)
  const int bloc_e = tid & 7;
  const int p_e = (tid >> 3) & 31;
  const int j0 = p_e * 2;
  // loader ids (tid>=256)
  const int s = tid & 255;
  char* grp = hx + (size_t)c * 65536;

  float cc0 = 0.f, cc1 = 0.f;
  __syncthreads();

  for (int t = 0; t < T_; ++t) {
    const unsigned tgt = (unsigned)t;
    float2 xgv[4];
    const int rw0 = (j0 >> 4) * 64 + (j0 & 15);
    if (epi) {
      // xg(t) loads issued now; latency hides under poll+MFMA; no wait here
      const float* xb = xg + ((size_t)t * 64 + bid) * 2048 + bloc_e * 256;
#pragma unroll
      for (int g = 0; g < 4; ++g) xgv[g] = *(const float2*)(xb + rw0 + g * 16);
      asm volatile("" ::: "memory");
    } else {
      // ---- poll/load h(t): full buffer, two r8-mapped 64B chunks ----
      const char* base = grp + (size_t)(t & 1) * 32768;
      const char* pA = base + (size_t)s * 64;
      const char* pB = base + (size_t)(s + 256) * 64;
      u32x4 qA[4], qB[4];
      ld4g(pA, qA, false);
      ld4g(pB, qB, false);
      for (unsigned a = 0;; ++a) {
        asm volatile("s_waitcnt vmcnt(0)" ::: "memory");
        __builtin_amdgcn_sched_barrier(0);
        unsigned bad = 0;
#pragma unroll
        for (int i = 0; i < 4; ++i) bad |= (qA[i][2] ^ tgt) | (qB[i][2] ^ tgt);
        if (!bad) break;
        __builtin_amdgcn_s_sleep(1);
        bool llc = (a & 1) != 0;
        ld4g(pA, qA, llc);
        ld4g(pB, qB, llc);
      }
      u32x4 hA = {qA[0][0], qA[1][0], qA[2][0], qA[3][0]};
      u32x4 lA = {qA[0][1], qA[1][1], qA[2][1], qA[3][1]};
      u32x4 hB = {qB[0][0], qB[1][0], qB[2][0], qB[3][0]};
      u32x4 lB = {qB[0][1], qB[1][1], qB[2][1], qB[3][1]};
      *(u32x4*)(&hhi[s >> 6][(s & 63) * 8]) = hA;
      *(u32x4*)(&hlo[s >> 6][(s & 63) * 8]) = lA;
      *(u32x4*)(&hhi[4 + (s >> 6)][(s & 63) * 8]) = hB;
      *(u32x4*)(&hlo[4 + (s >> 6)][(s & 63) * 8]) = lB;
    }
    LDSBAR();   // h(t) in LDS for all waves

    // ---- MFMA: gates_partial = h @ whh_slice (all 8 waves) ----
    f32x4 acc[2];
    acc[0] = (f32x4){0.f, 0.f, 0.f, 0.f};
    acc[1] = (f32x4){0.f, 0.f, 0.f, 0.f};
#pragma unroll
    for (int kt = 0; kt < 16; ++kt) {
      short8 ah = *(const short8*)(&hhi[lr][kt * 32 + lkg * 8]);
      short8 al = *(const short8*)(&hlo[lr][kt * 32 + lkg * 8]);
#pragma unroll
      for (int nt = 0; nt < 2; ++nt) {
        acc[nt] = __builtin_amdgcn_mfma_f32_16x16x32_bf16(ah, wreg[nt][kt], acc[nt], 0, 0, 0);
        acc[nt] = __builtin_amdgcn_mfma_f32_16x16x32_bf16(al, wreg[nt][kt], acc[nt], 0, 0, 0);
      }
    }
#pragma unroll
    for (int nt = 0; nt < 2; ++nt)
      *(f32x4*)(&gates[(w * 2 + nt) * 16 + lr][lkg * 4]) = acc[nt];
    LDSBAR();

    // ---- epilogue (waves 0-3): compute h(t+1), publish IMMEDIATELY ----
    if (epi) {
      float gv0[4], gv1[4];
#pragma unroll
      for (int g = 0; g < 4; ++g) {
        int rw = rw0 + g * 16;
        gv0[g] = gates[rw][bloc_e] + xgv[g].x;
        gv1[g] = gates[rw + 1][bloc_e] + xgv[g].y;
      }
      float cn0 = sigm(gv0[1]) * cc0 + sigm(gv0[0]) * tanh_(gv0[2]);
      float hn0 = sigm(gv0[3]) * tanh_(cn0);
      cc0 = cn0;
      float cn1 = sigm(gv1[1]) * cc1 + sigm(gv1[0]) * tanh_(gv1[2]);
      float hn1 = sigm(gv1[3]) * tanh_(cn1);
      cc1 = cn1;
      short hi0 = f2bf(hn0), hi1 = f2bf(hn1);
      short lo0 = f2bf(hn0 - bf2f(hi0)), lo1 = f2bf(hn1 - bf2f(hi1));
      u32x4 hv;
      hv[0] = (unsigned)(unsigned short)hi0 | ((unsigned)(unsigned short)hi1 << 16);
      hv[1] = (unsigned)(unsigned short)lo0 | ((unsigned)(unsigned short)lo1 << 16);
      hv[2] = tgt + 1u;
      hv[3] = tgt + 1u;
      char* pb = grp + (size_t)((t + 1) & 1) * 32768 +
                 ((size_t)(bloc_e * 256 + q * 32 + p_e)) * 16;
      asm volatile("global_store_dwordx4 %0, %1, off sc0" :: "v"(pb), "v"(hv) : "memory");
      asm volatile("global_store_dwordx4 %0, %1, off sc0 sc1" :: "v"(pb), "v"(hv) : "memory");
      float2 dv; dv.x = hn0; dv.y = hn1;
      *(float2*)(dec + ((size_t)(c * 8 + bloc_e) * T_ + t) * H_ + q * 64 + j0) = dv;
    }
    LDSBAR();
  }
}

// ---------------- attention + softmax + concat (f32) ----------------
__global__ __launch_bounds__(256) void attn_k(const float* __restrict__ dec,
                                              const float* __restrict__ enc,
                                              const int* __restrict__ lens,
                                              float* __restrict__ cat) {
  int bt = blockIdx.x;
  int b = bt / T_;
  __shared__ float dsh[H_];
  __shared__ float p[64];
  int tid = threadIdx.x;
  dsh[tid] = dec[(size_t)bt * H_ + tid];
  dsh[tid + 256] = dec[(size_t)bt * H_ + tid + 256];
  __syncthreads();
  int wid = tid >> 6, lane = tid & 63;
  int len = lens[b];
  for (int s = wid; s < S_; s += 4) {
    const float* er = enc + ((size_t)(b * S_ + s)) * H_ + lane * 8;
    float4 e0 = *(const float4*)er, e1 = *(const float4*)(er + 4);
    const float* dr = dsh + lane * 8;
    float sum = e0.x*dr[0] + e0.y*dr[1] + e0.z*dr[2] + e0.w*dr[3]
              + e1.x*dr[4] + e1.y*dr[5] + e1.z*dr[6] + e1.w*dr[7];
#pragma unroll
    for (int off = 32; off > 0; off >>= 1) sum += __shfl_down(sum, off);
    if (lane == 0) p[s] = sum + (s < len ? 0.f : -1.0e9f);
  }
  __syncthreads();
  if (wid == 0) {
    float v = (lane < S_) ? p[lane] : -INFINITY;
    float m = v;
#pragma unroll
    for (int off = 32; off > 0; off >>= 1) m = fmaxf(m, __shfl_down(m, off));
    m = __shfl(m, 0);
    float e = (lane < S_) ? expf(v - m) : 0.f;
    float ssum = e;
#pragma unroll
    for (int off = 32; off > 0; off >>= 1) ssum += __shfl_down(ssum, off);
    ssum = __shfl(ssum, 0);
    if (lane < S_) p[lane] = e / ssum;
  }
  __syncthreads();
  int h = tid * 2;
  float a0 = 0.f, a1 = 0.f;
  for (int s = 0; s < S_; ++s) {
    float ps = p[s];
    const float* er = enc + ((size_t)(b * S_ + s)) * H_ + h;
    a0 += ps * er[0];
    a1 += ps * er[1];
  }
  size_t base = (size_t)bt * (2 * H_);
  cat[base + h]          = dsh[h];
  cat[base + h + 1]      = dsh[h + 1];
  cat[base + H_ + h]     = a0;
  cat[base + H_ + h + 1] = a1;
}

extern "C" void kernel_launch(void* const* d_in, const int* in_sizes, int n_in,
                              void* d_out, int out_size, void* d_ws, size_t ws_size,
                              hipStream_t stream) {
  (void)in_sizes; (void)n_in; (void)out_size; (void)ws_size;
  const int*   indices = (const int*)d_in[0];
  const float* enc     = (const float*)d_in[1];
  const int*   de_lens = (const int*)d_in[2];
  const float* emb     = (const float*)d_in[3];
  const float* w_ih    = (const float*)d_in[4];
  const float* w_hh    = (const float*)d_in[5];
  const float* b_ih    = (const float*)d_in[6];
  const float* b_hh    = (const float*)d_in[7];
  const float* lin_w   = (const float*)d_in[8];
  const float* lin_b   = (const float*)d_in[9];
  const float* out_w   = (const float*)d_in[10];
  const float* out_b   = (const float*)d_in[11];
  float* outp = (float*)d_out;

  char* ws = (char*)d_ws;
  size_t off = 0;
  auto alloc = [&](size_t bytes) -> void* {
    void* p = ws + off; off += (bytes + 255) & ~(size_t)255; return p;
  };
  float* x      = (float*)alloc((size_t)BT_ * H_ * 4);
  float* xg     = (float*)alloc((size_t)BT_ * 4 * H_ * 4);      // [T,64,8,256]
  float* dec    = (float*)alloc((size_t)BT_ * H_ * 4);          // [B,T,H]
  float* cat    = (float*)alloc((size_t)BT_ * 2 * H_ * 4);
  short* ow_bf  = (short*)alloc((size_t)V_ * H_ * 2);
  short* whh_pk = (short*)alloc((size_t)L_ * 4 * H_ * H_ * 2);
  short* x_bf   = (short*)alloc((size_t)BT_ * H_ * 2);
  char*  hx     = (char*)alloc((size_t)8 * 2 * 32768);          // 512KB granules

  convbf_k<<<V_ * H_ / 8 / 256, 256, 0, stream>>>(out_w, ow_bf);
  pack_whh_k<<<L_ * 2048 * 64 / 256, 256, 0, stream>>>(w_hh, whh_pk);
  embed_k<<<BT_ * H_ / 256, 256, 0, stream>>>(indices, emb, x);

  for (int l = 0; l < L_; ++l) {
    gemm_a32_k<true><<<dim3(4 * H_ / 128, BT_ / 128), 256, 0, stream>>>(
        x, w_ih + (size_t)l * 4 * H_ * H_, b_ih + l * 4 * H_, b_hh + l * 4 * H_,
        xg, nullptr, BT_, 4 * H_, H_);
    hipMemsetAsync(hx, 0, (size_t)8 * 2 * 32768, stream);   // zero both parities
    lstm_seq_k<<<64, 512, 0, stream>>>(
        xg, whh_pk + (size_t)l * 4 * H_ * H_, hx, dec);
    attn_k<<<BT_, 256, 0, stream>>>(dec, enc, de_lens, cat);
    gemm_a32_k<false><<<dim3(H_ / 128, BT_ / 128), 256, 0, stream>>>(
        cat, lin_w + (size_t)l * H_ * 2 * H_, lin_b + l * H_, nullptr,
        x, (l == L_ - 1) ? x_bf : nullptr, BT_, H_, 2 * H_);
  }

  gemm_bb_k<<<30 * (V_ / 128), 256, 0, stream>>>(x_bf, ow_bf, out_b, outp);
}

// Round 12
// 955.970 us; speedup vs baseline: 1.2106x; 1.0251x over previous
//
#include <hip/hip_runtime.h>
#include <hip/hip_bf16.h>
#include <math.h>

#define B_ 64
#define T_ 60
#define S_ 60
#define H_ 512
#define V_ 32000
#define L_ 2
#define BT_ (B_*T_)
#define LDSROW2 72   // bf16 elems per LDS row for BK=64 tiles (2-way alias only)

typedef __attribute__((ext_vector_type(8))) short short8;
typedef __attribute__((ext_vector_type(4))) float f32x4;
typedef __attribute__((ext_vector_type(4))) unsigned int u32x4;

__device__ __forceinline__ short f2bf(float x) {
  __hip_bfloat16 h = __float2bfloat16(x);
  return __builtin_bit_cast(short, h);
}
__device__ __forceinline__ float bf2f(short s) {
  unsigned int u = ((unsigned int)(unsigned short)s) << 16;
  return __builtin_bit_cast(float, u);
}
__device__ __forceinline__ float sigm(float x) { return 1.f / (1.f + __expf(-x)); }
__device__ __forceinline__ float tanh_(float x) {
  float e = __expf(-2.f * fabsf(x));
  float t = (1.f - e) / (1.f + e);
  return x >= 0.f ? t : -t;
}

// 4 x 16B loads (64B contiguous per thread). llc=true -> LLC-coherent (sc0 sc1)
__device__ __forceinline__ void ld4g(const char* p, u32x4* q, bool llc) {
  if (llc)
    asm volatile("global_load_dwordx4 %0, %4, off sc0 sc1\n\t"
                 "global_load_dwordx4 %1, %4, off offset:16 sc0 sc1\n\t"
                 "global_load_dwordx4 %2, %4, off offset:32 sc0 sc1\n\t"
                 "global_load_dwordx4 %3, %4, off offset:48 sc0 sc1"
                 : "=v"(q[0]), "=v"(q[1]), "=v"(q[2]), "=v"(q[3]) : "v"(p));
  else
    asm volatile("global_load_dwordx4 %0, %4, off sc0\n\t"
                 "global_load_dwordx4 %1, %4, off offset:16 sc0\n\t"
                 "global_load_dwordx4 %2, %4, off offset:32 sc0\n\t"
                 "global_load_dwordx4 %3, %4, off offset:48 sc0"
                 : "=v"(q[0]), "=v"(q[1]), "=v"(q[2]), "=v"(q[3]) : "v"(p));
}

#define LDSBAR() do { \
    asm volatile("s_waitcnt lgkmcnt(0)" ::: "memory"); \
    __builtin_amdgcn_s_barrier(); \
    __builtin_amdgcn_sched_barrier(0); \
  } while (0)

// ---------------- f32 -> bf16 bulk convert ----------------
__global__ __launch_bounds__(256) void convbf_k(const float* __restrict__ src,
                                                short* __restrict__ dst) {
  int g = blockIdx.x * 256 + threadIdx.x;
  const float* s = src + (size_t)g * 8;
  float4 v0 = *(const float4*)s, v1 = *(const float4*)(s + 4);
  short8 o;
  o[0]=f2bf(v0.x); o[1]=f2bf(v0.y); o[2]=f2bf(v0.z); o[3]=f2bf(v0.w);
  o[4]=f2bf(v1.x); o[5]=f2bf(v1.y); o[6]=f2bf(v1.z); o[7]=f2bf(v1.w);
  *(short8*)(dst + (size_t)g * 8) = o;
}

// ---- pack whh[2,2048,512] f32 -> block-permuted fragment-ordered bf16 ----
__global__ __launch_bounds__(256) void pack_whh_k(const float* __restrict__ whh,
                                                  short* __restrict__ pk) {
  int idx = blockIdx.x * 256 + threadIdx.x;
  int l = idx >> 17, rem = idx & 131071;
  int n = rem >> 6, k8 = rem & 63;
  int g = n >> 9, j = n & 511;
  int np = (j >> 4) * 64 + g * 16 + (j & 15);
  const float* src = whh + ((size_t)l * 2048 + n) * 512 + k8 * 8;
  float4 v0 = *(const float4*)src, v1 = *(const float4*)(src + 4);
  short8 o;
  o[0]=f2bf(v0.x); o[1]=f2bf(v0.y); o[2]=f2bf(v0.z); o[3]=f2bf(v0.w);
  o[4]=f2bf(v1.x); o[5]=f2bf(v1.y); o[6]=f2bf(v1.z); o[7]=f2bf(v1.w);
  size_t dst = (size_t)l * (2048 * 512) + ((size_t)((np >> 4) * 64 + k8)) * 128 + (np & 15) * 8;
  *(short8*)(pk + dst) = o;
}

// ---------------- embedding gather -> hi/lo bf16 ----------------
__global__ __launch_bounds__(256) void embed_k(const int* __restrict__ idx,
                                               const float* __restrict__ emb,
                                               short* __restrict__ xhi,
                                               short* __restrict__ xlo) {
  int e = blockIdx.x * 256 + threadIdx.x;
  int bt = e >> 9, h = e & (H_ - 1);
  int row = idx[bt];
  float v = emb[(size_t)row * H_ + h];
  short hi = f2bf(v);
  xhi[e] = hi;
  xlo[e] = f2bf(v - bf2f(hi));
}

// ---- C = (Ahi+Alo)(bf16 pair) @ Bbf(bf16)^T + bias1[+bias2], BK=64 ----
// XPOSE: writes xg layout [T][64 blk][8 bloc][256 nploc] (f32)
// else:  writes Chi/Clo bf16 pair
template<bool XPOSE>
__global__ __launch_bounds__(256) void gemm_hl_k(
    const short* __restrict__ Ahi, const short* __restrict__ Alo,
    const short* __restrict__ Bbf,
    const float* __restrict__ bias1, const float* __restrict__ bias2,
    float* __restrict__ C, short* __restrict__ Chi, short* __restrict__ Clo,
    int M, int N, int K) {
  __shared__ short Ahs[128 * LDSROW2];
  __shared__ short Als[128 * LDSROW2];
  __shared__ short Bs[128 * LDSROW2];
  int tid = threadIdx.x;
  int bm = blockIdx.y * 128, bn = blockIdx.x * 128;
  int wid = tid >> 6, lane = tid & 63;
  int wr = wid >> 1, wc = wid & 1;
  int lrow = lane & 15;
  f32x4 acc[4][4];
#pragma unroll
  for (int i = 0; i < 4; ++i)
#pragma unroll
    for (int j = 0; j < 4; ++j) acc[i][j] = (f32x4){0.f, 0.f, 0.f, 0.f};

  int srow = tid >> 1, scol = (tid & 1) * 32;

  for (int k0 = 0; k0 < K; k0 += 64) {
    const short* ahp = Ahi + (size_t)(bm + srow) * K + k0 + scol;
    const short* alp = Alo + (size_t)(bm + srow) * K + k0 + scol;
    const short* bp  = Bbf + (size_t)(bn + srow) * K + k0 + scol;
#pragma unroll
    for (int u = 0; u < 4; ++u) {
      *(short8*)(Ahs + srow * LDSROW2 + scol + u * 8) = *(const short8*)(ahp + u * 8);
      *(short8*)(Als + srow * LDSROW2 + scol + u * 8) = *(const short8*)(alp + u * 8);
      *(short8*)(Bs  + srow * LDSROW2 + scol + u * 8) = *(const short8*)(bp  + u * 8);
    }
    __syncthreads();
#pragma unroll
    for (int kk = 0; kk < 2; ++kk) {
      int lk = kk * 32 + (lane >> 4) * 8;
      short8 ah[4], al[4], bfr[4];
#pragma unroll
      for (int i = 0; i < 4; ++i) {
        ah[i] = *(const short8*)(Ahs + (wr * 64 + i * 16 + lrow) * LDSROW2 + lk);
        al[i] = *(const short8*)(Als + (wr * 64 + i * 16 + lrow) * LDSROW2 + lk);
      }
#pragma unroll
      for (int j = 0; j < 4; ++j)
        bfr[j] = *(const short8*)(Bs + (wc * 64 + j * 16 + lrow) * LDSROW2 + lk);
#pragma unroll
      for (int i = 0; i < 4; ++i)
#pragma unroll
        for (int j = 0; j < 4; ++j) {
          acc[i][j] = __builtin_amdgcn_mfma_f32_16x16x32_bf16(ah[i], bfr[j], acc[i][j], 0, 0, 0);
          acc[i][j] = __builtin_amdgcn_mfma_f32_16x16x32_bf16(al[i], bfr[j], acc[i][j], 0, 0, 0);
        }
    }
    __syncthreads();
  }

#pragma unroll
  for (int j = 0; j < 4; ++j) {
    int col = bn + wc * 64 + j * 16 + lrow;
    float bv = bias1[col] + (bias2 ? bias2[col] : 0.f);
#pragma unroll
    for (int i = 0; i < 4; ++i) {
#pragma unroll
      for (int r = 0; r < 4; ++r) {
        int row = bm + wr * 64 + i * 16 + (lane >> 4) * 4 + r;
        float v = acc[i][j][r] + bv;
        if (XPOSE) {
          int b = row / T_, t = row - b * T_;
          int g = col >> 9, jg = col & 511;
          int c8 = b >> 3, bloc = b & 7, q = jg >> 6;
          int nploc = ((jg >> 4) & 3) * 64 + g * 16 + (jg & 15);
          C[(((size_t)t * 64 + q * 8 + c8) * 8 + bloc) * 256 + nploc] = v;
        } else {
          short hi = f2bf(v);
          Chi[(size_t)row * N + col] = hi;
          Clo[(size_t)row * N + col] = f2bf(v - bf2f(hi));
        }
      }
    }
  }
}

// --------- final: C = A(bf16) @ Bbf(bf16)^T + bias, BK=64, nt C-stores ------
__global__ __launch_bounds__(256) void gemm_bb_k(
    const short* __restrict__ A, const short* __restrict__ Bbf,
    const float* __restrict__ bias, float* __restrict__ C) {
  const int N = V_, K = H_;
  int n = blockIdx.x;
  int xcd = n & 7, pos = n >> 3;
  int base = (xcd < 4) ? xcd * 938 : 4 * 938 + (xcd - 4) * 937;
  int wg = base + pos;
  int bm = (wg % 30) * 128;
  int bn = (wg / 30) * 128;

  __shared__ short As[128 * LDSROW2];
  __shared__ short Bs[128 * LDSROW2];
  int tid = threadIdx.x;
  int wid = tid >> 6, lane = tid & 63;
  int wr = wid >> 1, wc = wid & 1;
  int lrow = lane & 15;
  f32x4 acc[4][4];
#pragma unroll
  for (int i = 0; i < 4; ++i)
#pragma unroll
    for (int j = 0; j < 4; ++j) acc[i][j] = (f32x4){0.f, 0.f, 0.f, 0.f};

  int srow = tid >> 2, scol = (tid & 3) * 16;

  for (int k0 = 0; k0 < K; k0 += 64) {
#pragma unroll
    for (int it = 0; it < 2; ++it) {
      int r = srow + it * 64;
      const short* ap = A + (size_t)(bm + r) * K + k0 + scol;
      short8 a0 = *(const short8*)ap, a1 = *(const short8*)(ap + 8);
      *(short8*)(As + r * LDSROW2 + scol) = a0;
      *(short8*)(As + r * LDSROW2 + scol + 8) = a1;
      const short* bp = Bbf + (size_t)(bn + r) * K + k0 + scol;
      short8 b0 = *(const short8*)bp, b1 = *(const short8*)(bp + 8);
      *(short8*)(Bs + r * LDSROW2 + scol) = b0;
      *(short8*)(Bs + r * LDSROW2 + scol + 8) = b1;
    }
    __syncthreads();
#pragma unroll
    for (int kk = 0; kk < 2; ++kk) {
      int lk = kk * 32 + (lane >> 4) * 8;
      short8 af[4], bfr[4];
#pragma unroll
      for (int i = 0; i < 4; ++i)
        af[i] = *(const short8*)(As + (wr * 64 + i * 16 + lrow) * LDSROW2 + lk);
#pragma unroll
      for (int j = 0; j < 4; ++j)
        bfr[j] = *(const short8*)(Bs + (wc * 64 + j * 16 + lrow) * LDSROW2 + lk);
#pragma unroll
      for (int i = 0; i < 4; ++i)
#pragma unroll
        for (int j = 0; j < 4; ++j)
          acc[i][j] = __builtin_amdgcn_mfma_f32_16x16x32_bf16(af[i], bfr[j], acc[i][j], 0, 0, 0);
    }
    __syncthreads();
  }

#pragma unroll
  for (int j = 0; j < 4; ++j) {
    int col = bn + wc * 64 + j * 16 + lrow;
    float bv = bias[col];
#pragma unroll
    for (int i = 0; i < 4; ++i)
#pragma unroll
      for (int r = 0; r < 4; ++r) {
        int row = bm + wr * 64 + i * 16 + (lane >> 4) * 4 + r;
        float v = acc[i][j][r] + bv;
        float* cp = C + (size_t)row * N + col;
        asm volatile("global_store_dword %0, %1, off nt" :: "v"(cp), "v"(v) : "memory");
      }
  }
}

// ---- persistent LSTM: 8 intra-XCD groups x 8 j-blocks, tagged granules ----
// (r11 structure, unchanged)
__global__ __launch_bounds__(512, 2) void lstm_seq_k(
    const float* __restrict__ xg,      // [T][64 blk][8 bloc][256 nploc]
    const short* __restrict__ whh_pk,  // packed bf16
    char* __restrict__ hx,             // 8 groups x 2 x 32KB, zeroed per layer
    float* __restrict__ dec) {         // [B,T,H]
  __shared__ short hhi[16][520];
  __shared__ short hlo[16][520];
  __shared__ float gates[256][20];
  const int tid = threadIdx.x;
  const int bid = blockIdx.x;
  const int c = bid & 7, q = bid >> 3;
  const int w = tid >> 6, lane = tid & 63;
  const int lr = lane & 15, lkg = lane >> 4;

  for (int i = tid; i < 16 * 520; i += 512) {
    ((short*)hhi)[i] = 0;
    ((short*)hlo)[i] = 0;
  }

  short8 wreg[2][16];
#pragma unroll
  for (int nt = 0; nt < 2; ++nt)
#pragma unroll
    for (int kt = 0; kt < 16; ++kt)
      wreg[nt][kt] = *(const short8*)(whh_pk +
          ((size_t)((q * 16 + w * 2 + nt) * 64 + kt * 4 + lkg)) * 128 + lr * 8);

  const bool epi = (tid < 256);
  const int bloc_e = tid & 7;
  const int p_e = (tid >> 3) & 31;
  const int j0 = p_e * 2;
  const int s = tid & 255;
  char* grp = hx + (size_t)c * 65536;

  float cc0 = 0.f, cc1 = 0.f;
  __syncthreads();

  for (int t = 0; t < T_; ++t) {
    const unsigned tgt = (unsigned)t;
    float2 xgv[4];
    const int rw0 = (j0 >> 4) * 64 + (j0 & 15);
    if (epi) {
      const float* xb = xg + ((size_t)t * 64 + bid) * 2048 + bloc_e * 256;
#pragma unroll
      for (int g = 0; g < 4; ++g) xgv[g] = *(const float2*)(xb + rw0 + g * 16);
      asm volatile("" ::: "memory");
    } else {
      const char* base = grp + (size_t)(t & 1) * 32768;
      const char* pA = base + (size_t)s * 64;
      const char* pB = base + (size_t)(s + 256) * 64;
      u32x4 qA[4], qB[4];
      ld4g(pA, qA, false);
      ld4g(pB, qB, false);
      for (unsigned a = 0;; ++a) {
        asm volatile("s_waitcnt vmcnt(0)" ::: "memory");
        __builtin_amdgcn_sched_barrier(0);
        unsigned bad = 0;
#pragma unroll
        for (int i = 0; i < 4; ++i) bad |= (qA[i][2] ^ tgt) | (qB[i][2] ^ tgt);
        if (!bad) break;
        __builtin_amdgcn_s_sleep(1);
        bool llc = (a & 1) != 0;
        ld4g(pA, qA, llc);
        ld4g(pB, qB, llc);
      }
      u32x4 hA = {qA[0][0], qA[1][0], qA[2][0], qA[3][0]};
      u32x4 lA = {qA[0][1], qA[1][1], qA[2][1], qA[3][1]};
      u32x4 hB = {qB[0][0], qB[1][0], qB[2][0], qB[3][0]};
      u32x4 lB = {qB[0][1], qB[1][1], qB[2][1], qB[3][1]};
      *(u32x4*)(&hhi[s >> 6][(s & 63) * 8]) = hA;
      *(u32x4*)(&hlo[s >> 6][(s & 63) * 8]) = lA;
      *(u32x4*)(&hhi[4 + (s >> 6)][(s & 63) * 8]) = hB;
      *(u32x4*)(&hlo[4 + (s >> 6)][(s & 63) * 8]) = lB;
    }
    LDSBAR();

    f32x4 acc[2];
    acc[0] = (f32x4){0.f, 0.f, 0.f, 0.f};
    acc[1] = (f32x4){0.f, 0.f, 0.f, 0.f};
#pragma unroll
    for (int kt = 0; kt < 16; ++kt) {
      short8 ah = *(const short8*)(&hhi[lr][kt * 32 + lkg * 8]);
      short8 al = *(const short8*)(&hlo[lr][kt * 32 + lkg * 8]);
#pragma unroll
      for (int nt = 0; nt < 2; ++nt) {
        acc[nt] = __builtin_amdgcn_mfma_f32_16x16x32_bf16(ah, wreg[nt][kt], acc[nt], 0, 0, 0);
        acc[nt] = __builtin_amdgcn_mfma_f32_16x16x32_bf16(al, wreg[nt][kt], acc[nt], 0, 0, 0);
      }
    }
#pragma unroll
    for (int nt = 0; nt < 2; ++nt)
      *(f32x4*)(&gates[(w * 2 + nt) * 16 + lr][lkg * 4]) = acc[nt];
    LDSBAR();

    if (epi) {
      float gv0[4], gv1[4];
#pragma unroll
      for (int g = 0; g < 4; ++g) {
        int rw = rw0 + g * 16;
        gv0[g] = gates[rw][bloc_e] + xgv[g].x;
        gv1[g] = gates[rw + 1][bloc_e] + xgv[g].y;
      }
      float cn0 = sigm(gv0[1]) * cc0 + sigm(gv0[0]) * tanh_(gv0[2]);
      float hn0 = sigm(gv0[3]) * tanh_(cn0);
      cc0 = cn0;
      float cn1 = sigm(gv1[1]) * cc1 + sigm(gv1[0]) * tanh_(gv1[2]);
      float hn1 = sigm(gv1[3]) * tanh_(cn1);
      cc1 = cn1;
      short hi0 = f2bf(hn0), hi1 = f2bf(hn1);
      short lo0 = f2bf(hn0 - bf2f(hi0)), lo1 = f2bf(hn1 - bf2f(hi1));
      u32x4 hv;
      hv[0] = (unsigned)(unsigned short)hi0 | ((unsigned)(unsigned short)hi1 << 16);
      hv[1] = (unsigned)(unsigned short)lo0 | ((unsigned)(unsigned short)lo1 << 16);
      hv[2] = tgt + 1u;
      hv[3] = tgt + 1u;
      char* pb = grp + (size_t)((t + 1) & 1) * 32768 +
                 ((size_t)(bloc_e * 256 + q * 32 + p_e)) * 16;
      asm volatile("global_store_dwordx4 %0, %1, off sc0" :: "v"(pb), "v"(hv) : "memory");
      asm volatile("global_store_dwordx4 %0, %1, off sc0 sc1" :: "v"(pb), "v"(hv) : "memory");
      float2 dv; dv.x = hn0; dv.y = hn1;
      *(float2*)(dec + ((size_t)(c * 8 + bloc_e) * T_ + t) * H_ + q * 64 + j0) = dv;
    }
    LDSBAR();
  }
}

// ------- attention + softmax + concat (f32 compute, hi/lo bf16 out) --------
__global__ __launch_bounds__(256) void attn_k(const float* __restrict__ dec,
                                              const float* __restrict__ enc,
                                              const int* __restrict__ lens,
                                              short* __restrict__ cat_hi,
                                              short* __restrict__ cat_lo) {
  int bt = blockIdx.x;
  int b = bt / T_;
  __shared__ float dsh[H_];
  __shared__ float p[64];
  int tid = threadIdx.x;
  dsh[tid] = dec[(size_t)bt * H_ + tid];
  dsh[tid + 256] = dec[(size_t)bt * H_ + tid + 256];
  __syncthreads();
  int wid = tid >> 6, lane = tid & 63;
  int len = lens[b];
  for (int s = wid; s < S_; s += 4) {
    const float* er = enc + ((size_t)(b * S_ + s)) * H_ + lane * 8;
    float4 e0 = *(const float4*)er, e1 = *(const float4*)(er + 4);
    const float* dr = dsh + lane * 8;
    float sum = e0.x*dr[0] + e0.y*dr[1] + e0.z*dr[2] + e0.w*dr[3]
              + e1.x*dr[4] + e1.y*dr[5] + e1.z*dr[6] + e1.w*dr[7];
#pragma unroll
    for (int off = 32; off > 0; off >>= 1) sum += __shfl_down(sum, off);
    if (lane == 0) p[s] = sum + (s < len ? 0.f : -1.0e9f);
  }
  __syncthreads();
  if (wid == 0) {
    float v = (lane < S_) ? p[lane] : -INFINITY;
    float m = v;
#pragma unroll
    for (int off = 32; off > 0; off >>= 1) m = fmaxf(m, __shfl_down(m, off));
    m = __shfl(m, 0);
    float e = (lane < S_) ? expf(v - m) : 0.f;
    float ssum = e;
#pragma unroll
    for (int off = 32; off > 0; off >>= 1) ssum += __shfl_down(ssum, off);
    ssum = __shfl(ssum, 0);
    if (lane < S_) p[lane] = e / ssum;
  }
  __syncthreads();
  int h = tid * 2;
  float a0 = 0.f, a1 = 0.f;
  for (int s = 0; s < S_; ++s) {
    float ps = p[s];
    const float* er = enc + ((size_t)(b * S_ + s)) * H_ + h;
    a0 += ps * er[0];
    a1 += ps * er[1];
  }
  size_t base = (size_t)bt * (2 * H_);
  float vv[4] = {dsh[h], dsh[h + 1], a0, a1};
  int   oo[4] = {h, h + 1, H_ + h, H_ + h + 1};
#pragma unroll
  for (int i = 0; i < 4; ++i) {
    short hi = f2bf(vv[i]);
    cat_hi[base + oo[i]] = hi;
    cat_lo[base + oo[i]] = f2bf(vv[i] - bf2f(hi));
  }
}

extern "C" void kernel_launch(void* const* d_in, const int* in_sizes, int n_in,
                              void* d_out, int out_size, void* d_ws, size_t ws_size,
                              hipStream_t stream) {
  (void)in_sizes; (void)n_in; (void)out_size; (void)ws_size;
  const int*   indices = (const int*)d_in[0];
  const float* enc     = (const float*)d_in[1];
  const int*   de_lens = (const int*)d_in[2];
  const float* emb     = (const float*)d_in[3];
  const float* w_ih    = (const float*)d_in[4];
  const float* w_hh    = (const float*)d_in[5];
  const float* b_ih    = (const float*)d_in[6];
  const float* b_hh    = (const float*)d_in[7];
  const float* lin_w   = (const float*)d_in[8];
  const float* lin_b   = (const float*)d_in[9];
  const float* out_w   = (const float*)d_in[10];
  const float* out_b   = (const float*)d_in[11];
  float* outp = (float*)d_out;

  char* ws = (char*)d_ws;
  size_t off = 0;
  auto alloc = [&](size_t bytes) -> void* {
    void* p = ws + off; off += (bytes + 255) & ~(size_t)255; return p;
  };
  short* x_hi   = (short*)alloc((size_t)BT_ * H_ * 2);
  short* x_lo   = (short*)alloc((size_t)BT_ * H_ * 2);
  float* xg     = (float*)alloc((size_t)BT_ * 4 * H_ * 4);      // [T,64,8,256]
  float* dec    = (float*)alloc((size_t)BT_ * H_ * 4);          // [B,T,H]
  short* cat_hi = (short*)alloc((size_t)BT_ * 2 * H_ * 2);
  short* cat_lo = (short*)alloc((size_t)BT_ * 2 * H_ * 2);
  short* ow_bf  = (short*)alloc((size_t)V_ * H_ * 2);
  short* wih_bf = (short*)alloc((size_t)L_ * 4 * H_ * H_ * 2);
  short* linw_bf= (short*)alloc((size_t)L_ * H_ * 2 * H_ * 2);
  short* whh_pk = (short*)alloc((size_t)L_ * 4 * H_ * H_ * 2);
  char*  hx     = (char*)alloc((size_t)8 * 2 * 32768);          // 512KB granules

  convbf_k<<<V_ * H_ / 8 / 256, 256, 0, stream>>>(out_w, ow_bf);
  convbf_k<<<L_ * 4 * H_ * H_ / 8 / 256, 256, 0, stream>>>(w_ih, wih_bf);
  convbf_k<<<L_ * H_ * 2 * H_ / 8 / 256, 256, 0, stream>>>(lin_w, linw_bf);
  pack_whh_k<<<L_ * 2048 * 64 / 256, 256, 0, stream>>>(w_hh, whh_pk);
  embed_k<<<BT_ * H_ / 256, 256, 0, stream>>>(indices, emb, x_hi, x_lo);

  for (int l = 0; l < L_; ++l) {
    gemm_hl_k<true><<<dim3(4 * H_ / 128, BT_ / 128), 256, 0, stream>>>(
        x_hi, x_lo, wih_bf + (size_t)l * 4 * H_ * H_,
        b_ih + l * 4 * H_, b_hh + l * 4 * H_,
        xg, nullptr, nullptr, BT_, 4 * H_, H_);
    hipMemsetAsync(hx, 0, (size_t)8 * 2 * 32768, stream);   // zero both parities
    lstm_seq_k<<<64, 512, 0, stream>>>(
        xg, whh_pk + (size_t)l * 4 * H_ * H_, hx, dec);
    attn_k<<<BT_, 256, 0, stream>>>(dec, enc, de_lens, cat_hi, cat_lo);
    gemm_hl_k<false><<<dim3(H_ / 128, BT_ / 128), 256, 0, stream>>>(
        cat_hi, cat_lo, linw_bf + (size_t)l * H_ * 2 * H_,
        lin_b + l * H_, nullptr,
        nullptr, x_hi, x_lo, BT_, H_, 2 * H_);
  }

  gemm_bb_k<<<30 * (V_ / 128), 256, 0, stream>>>(x_hi, ow_bf, out_b, outp);
}